// Round 2
// baseline (255.938 us; speedup 1.0000x reference)
//
#include <hip/hip_runtime.h>

typedef float f4v __attribute__((ext_vector_type(4), aligned(4)));
typedef float f2v __attribute__((ext_vector_type(2), aligned(4)));

__device__ __forceinline__ float fast_tanh(float x) {
  // tanh(x) = 1 - 2/(1 + exp2(x * 2*log2(e)))
  float t = x * 2.8853900817779268f;
  float e = __builtin_amdgcn_exp2f(t);
  float r = __builtin_amdgcn_rcpf(e + 1.0f);
  return 1.0f - 2.0f * r;
}

// load 12 cols (3 x dwordx4) of row `rowoff` for both channels into d0/d1
__device__ __forceinline__ void ldrow(const float* __restrict__ base, int rowoff,
                                      float (&d0)[12], float (&d1)[12]) {
#pragma unroll
  for (int kk = 0; kk < 3; ++kk) {
    f4v a = *reinterpret_cast<const f4v*>(base + rowoff * 21 + 4 * kk);
    f4v b = *reinterpret_cast<const f4v*>(base + 273 + rowoff * 21 + 4 * kk);
#pragma unroll
    for (int l = 0; l < 4; ++l) {
      d0[4 * kk + l] = a[l];
      d1[4 * kk + l] = b[l];
    }
  }
}

// one output row: 9 positions, window rows in slots S0,S1,S2 (static)
template <int S0, int S1, int S2>
__device__ __forceinline__ void row_body(
    const float (&W0)[4][12], const float (&W1)[4][12],
    const float* __restrict__ dww, const float* __restrict__ pww,
    const float* __restrict__ pwb, const float* __restrict__ cvw,
    const float* __restrict__ cvb, float (&pool)[5][3]) {
#pragma unroll
  for (int j = 0; j < 9; ++j) {
    float d0 = W0[S0][j] * dww[0] + W0[S0][j + 1] * dww[1] + W0[S0][j + 2] * dww[2]
             + W0[S1][j] * dww[3] + W0[S1][j + 1] * dww[4] + W0[S1][j + 2] * dww[5]
             + W0[S2][j] * dww[6] + W0[S2][j + 1] * dww[7] + W0[S2][j + 2] * dww[8];
    float d1 = W1[S0][j] * dww[9]  + W1[S0][j + 1] * dww[10] + W1[S0][j + 2] * dww[11]
             + W1[S1][j] * dww[12] + W1[S1][j + 1] * dww[13] + W1[S1][j + 2] * dww[14]
             + W1[S2][j] * dww[15] + W1[S2][j + 1] * dww[16] + W1[S2][j + 2] * dww[17];
    float aa[5];
#pragma unroll
    for (int p = 0; p < 5; ++p)
      aa[p] = fast_tanh(pwb[p] + pww[2 * p] * d0 + pww[2 * p + 1] * d1);
#pragma unroll
    for (int q = 0; q < 5; ++q) {
      float acc = cvb[q];
#pragma unroll
      for (int p = 0; p < 5; ++p) acc += cvw[5 * q + p] * aa[p];
      pool[q][j / 3] += fast_tanh(acc);
    }
  }
}

// pool row-group RR complete: tanh + partial fc1 accumulation (this thread's 3 cols)
template <int RR>
__device__ __forceinline__ void pool_finish(float (&pool)[5][3], float (&h1a)[16],
                                            const float* __restrict__ w1t) {
#pragma unroll
  for (int c = 0; c < 5; ++c)
#pragma unroll
    for (int pc = 0; pc < 3; ++pc) {
      float pv = fast_tanh(pool[c][pc] * (1.0f / 9.0f));
      pool[c][pc] = 0.0f;
#pragma unroll
      for (int o = 0; o < 16; ++o)
        h1a[o] += pv * w1t[o * 90 + c * 18 + RR * 6 + pc];
    }
}

__global__ __launch_bounds__(256, 3) void smartpixel_kernel(
    const float* __restrict__ x, const float* __restrict__ dww,
    const float* __restrict__ pww, const float* __restrict__ pwb,
    const float* __restrict__ cvw, const float* __restrict__ cvb,
    const float* __restrict__ w1, const float* __restrict__ b1,
    const float* __restrict__ w2, const float* __restrict__ b2,
    const float* __restrict__ w3, const float* __restrict__ b3,
    float* __restrict__ out, int nsamp) {
  const int g = blockIdx.x * 256 + threadIdx.x;
  const int s = g >> 1;          // sample
  const int t = g & 1;           // column-half: t=0 -> out cols 0..8, t=1 -> 9..17
  if (s >= nsamp) return;
  // t=0 loads input cols 0..11 (bytes 0..47); t=1 loads cols 9..20 (bytes 36..83)
  const float* xb = x + (long)s * 546 + t * 9;

  float W0[4][12], W1[4][12];    // 4-slot rotating row window, 2 channels
  ldrow(xb, 0, W0[0], W1[0]);
  ldrow(xb, 1, W0[1], W1[1]);
  ldrow(xb, 2, W0[2], W1[2]);

  float pool[5][3];
#pragma unroll
  for (int c = 0; c < 5; ++c)
#pragma unroll
    for (int pc = 0; pc < 3; ++pc) pool[c][pc] = 0.0f;

  float h1a[16];
#pragma unroll
  for (int o = 0; o < 16; ++o) h1a[o] = (t == 0) ? b1[o] : 0.0f;

  const float* w1t = w1 + 3 * t;  // this thread's fc1 feature-column base

#pragma unroll 1
  for (int ig = 0; ig < 2; ++ig) {
    const float* xr = xb + ig * 84;  // rows 4*ig ...
    // k=0: row i=4ig, prefetch row 4ig+3 -> slot 3
    ldrow(xr, 3, W0[3], W1[3]);
    row_body<0, 1, 2>(W0, W1, dww, pww, pwb, cvw, cvb, pool);
    // k=1: row i=4ig+1, prefetch row 4ig+4 -> slot 0
    ldrow(xr, 4, W0[0], W1[0]);
    row_body<1, 2, 3>(W0, W1, dww, pww, pwb, cvw, cvb, pool);
    if (ig == 1) pool_finish<1>(pool, h1a, w1t);   // after row 5
    // k=2: row i=4ig+2, prefetch row 4ig+5 -> slot 1
    ldrow(xr, 5, W0[1], W1[1]);
    row_body<2, 3, 0>(W0, W1, dww, pww, pwb, cvw, cvb, pool);
    if (ig == 0) pool_finish<0>(pool, h1a, w1t);   // after row 2
    // k=3: row i=4ig+3, prefetch row 4ig+6 -> slot 2
    ldrow(xr, 6, W0[2], W1[2]);
    row_body<3, 0, 1>(W0, W1, dww, pww, pwb, cvw, cvb, pool);
  }
  // epilogue: row 8 (slots 0,1,2 hold rows 8,9,10)
  row_body<0, 1, 2>(W0, W1, dww, pww, pwb, cvw, cvb, pool);
  pool_finish<2>(pool, h1a, w1t);

  // combine fc1 partials across the sample's thread pair
#pragma unroll
  for (int o = 0; o < 16; ++o) h1a[o] += __shfl_xor(h1a[o], 1, 64);

  float h1[16];
#pragma unroll
  for (int k = 0; k < 16; ++k) h1[k] = fast_tanh(h1a[k]);

  float h2[16];
#pragma unroll
  for (int o = 0; o < 16; ++o) {
    float acc = b2[o];
#pragma unroll
    for (int k = 0; k < 16; ++k) acc += h1[k] * w2[o * 16 + k];
    h2[o] = fast_tanh(acc);
  }

  // fc3: each thread computes its 7 outputs, stores 28 contiguous bytes
  const int ob = 7 * t;
  float ov[7];
#pragma unroll
  for (int oo = 0; oo < 7; ++oo) {
    float acc = b3[ob + oo];
#pragma unroll
    for (int k = 0; k < 16; ++k) acc += h2[k] * w3[(ob + oo) * 16 + k];
    ov[oo] = acc;
  }
  float* po = out + (long)s * 14 + ob;
  f4v v4; v4[0] = ov[0]; v4[1] = ov[1]; v4[2] = ov[2]; v4[3] = ov[3];
  *reinterpret_cast<f4v*>(po) = v4;
  f2v v2; v2[0] = ov[4]; v2[1] = ov[5];
  *reinterpret_cast<f2v*>(po + 4) = v2;
  po[6] = ov[6];
}

extern "C" void kernel_launch(void* const* d_in, const int* in_sizes, int n_in,
                              void* d_out, int out_size, void* d_ws, size_t ws_size,
                              hipStream_t stream) {
  const float* x      = (const float*)d_in[0];
  const float* dw_w   = (const float*)d_in[1];
  const float* pw_w   = (const float*)d_in[2];
  const float* pw_b   = (const float*)d_in[3];
  const float* conv_w = (const float*)d_in[4];
  const float* conv_b = (const float*)d_in[5];
  const float* w1     = (const float*)d_in[6];
  const float* b1     = (const float*)d_in[7];
  const float* w2     = (const float*)d_in[8];
  const float* b2     = (const float*)d_in[9];
  const float* w3     = (const float*)d_in[10];
  const float* b3     = (const float*)d_in[11];
  float* out = (float*)d_out;

  int nsamp = in_sizes[0] / 546;
  long nthreads = 2L * nsamp;
  int blocks = (int)((nthreads + 255) / 256);
  smartpixel_kernel<<<blocks, 256, 0, stream>>>(
      x, dw_w, pw_w, pw_b, conv_w, conv_b, w1, b1, w2, b2, w3, b3, out, nsamp);
}

// Round 3
// 243.658 us; speedup vs baseline: 1.0504x; 1.0504x over previous
//
#include <hip/hip_runtime.h>

typedef float f4v __attribute__((ext_vector_type(4), aligned(4)));
typedef float f2v __attribute__((ext_vector_type(2), aligned(4)));

__device__ __forceinline__ float fast_tanh(float x) {
  // tanh(x) = 1 - 2/(1 + exp2(x * 2*log2(e)))
  float t = x * 2.8853900817779268f;
  float e = __builtin_amdgcn_exp2f(t);
  float r = __builtin_amdgcn_rcpf(e + 1.0f);
  return 1.0f - 2.0f * r;
}

// load 12 cols (3 x dwordx4) of row `rowoff` for both channels into d0/d1
__device__ __forceinline__ void ldrow(const float* __restrict__ base, int rowoff,
                                      float (&d0)[12], float (&d1)[12]) {
#pragma unroll
  for (int kk = 0; kk < 3; ++kk) {
    f4v a = *reinterpret_cast<const f4v*>(base + rowoff * 21 + 4 * kk);
    f4v b = *reinterpret_cast<const f4v*>(base + 273 + rowoff * 21 + 4 * kk);
#pragma unroll
    for (int l = 0; l < 4; ++l) {
      d0[4 * kk + l] = a[l];
      d1[4 * kk + l] = b[l];
    }
  }
}

// one output row: 9 positions, window rows in slots S0,S1,S2 (static)
template <int S0, int S1, int S2>
__device__ __forceinline__ void row_body(
    const float (&W0)[4][12], const float (&W1)[4][12],
    const float* __restrict__ dww, const float* __restrict__ pww,
    const float* __restrict__ pwb, const float* __restrict__ cvw,
    const float* __restrict__ cvb, float (&pool)[5][3]) {
#pragma unroll
  for (int j = 0; j < 9; ++j) {
    float d0 = W0[S0][j] * dww[0] + W0[S0][j + 1] * dww[1] + W0[S0][j + 2] * dww[2]
             + W0[S1][j] * dww[3] + W0[S1][j + 1] * dww[4] + W0[S1][j + 2] * dww[5]
             + W0[S2][j] * dww[6] + W0[S2][j + 1] * dww[7] + W0[S2][j + 2] * dww[8];
    float d1 = W1[S0][j] * dww[9]  + W1[S0][j + 1] * dww[10] + W1[S0][j + 2] * dww[11]
             + W1[S1][j] * dww[12] + W1[S1][j + 1] * dww[13] + W1[S1][j + 2] * dww[14]
             + W1[S2][j] * dww[15] + W1[S2][j + 1] * dww[16] + W1[S2][j + 2] * dww[17];
    float aa[5];
#pragma unroll
    for (int p = 0; p < 5; ++p)
      aa[p] = fast_tanh(pwb[p] + pww[2 * p] * d0 + pww[2 * p + 1] * d1);
#pragma unroll
    for (int q = 0; q < 5; ++q) {
      float acc = cvb[q];
#pragma unroll
      for (int p = 0; p < 5; ++p) acc += cvw[5 * q + p] * aa[p];
      pool[q][j / 3] += fast_tanh(acc);
    }
  }
}

// pool row-group RR complete: tanh + partial fc1 accumulation (this thread's 3 cols)
template <int RR>
__device__ __forceinline__ void pool_finish(float (&pool)[5][3], float (&h1a)[16],
                                            const float* __restrict__ w1t) {
#pragma unroll
  for (int c = 0; c < 5; ++c)
#pragma unroll
    for (int pc = 0; pc < 3; ++pc) {
      float pv = fast_tanh(pool[c][pc] * (1.0f / 9.0f));
      pool[c][pc] = 0.0f;
#pragma unroll
      for (int o = 0; o < 16; ++o)
        h1a[o] += pv * w1t[o * 90 + c * 18 + RR * 6 + pc];
    }
}

__global__ __launch_bounds__(256)
__attribute__((amdgpu_waves_per_eu(3, 3)))
void smartpixel_kernel(
    const float* __restrict__ x, const float* __restrict__ dww,
    const float* __restrict__ pww, const float* __restrict__ pwb,
    const float* __restrict__ cvw, const float* __restrict__ cvb,
    const float* __restrict__ w1, const float* __restrict__ b1,
    const float* __restrict__ w2, const float* __restrict__ b2,
    const float* __restrict__ w3, const float* __restrict__ b3,
    float* __restrict__ out, int nsamp) {
  const int g = blockIdx.x * 256 + threadIdx.x;
  const int s = g >> 1;          // sample
  const int t = g & 1;           // column-half: t=0 -> out cols 0..8, t=1 -> 9..17
  if (s >= nsamp) return;
  // t=0 loads input cols 0..11; t=1 loads cols 9..20
  const float* xb = x + (long)s * 546 + t * 9;

  float W0[4][12], W1[4][12];    // 4-slot rotating row window, 2 channels
  ldrow(xb, 0, W0[0], W1[0]);
  ldrow(xb, 1, W0[1], W1[1]);
  ldrow(xb, 2, W0[2], W1[2]);

  float pool[5][3];
#pragma unroll
  for (int c = 0; c < 5; ++c)
#pragma unroll
    for (int pc = 0; pc < 3; ++pc) pool[c][pc] = 0.0f;

  float h1a[16];
#pragma unroll
  for (int o = 0; o < 16; ++o) h1a[o] = (t == 0) ? b1[o] : 0.0f;

  const float* w1t = w1 + 3 * t;  // this thread's fc1 feature-column base

#pragma unroll 1
  for (int ig = 0; ig < 2; ++ig) {
    const float* xr = xb + ig * 84;  // rows 4*ig ...
    // k=0: row i=4ig, prefetch row 4ig+3 -> slot 3
    ldrow(xr, 3, W0[3], W1[3]);
    row_body<0, 1, 2>(W0, W1, dww, pww, pwb, cvw, cvb, pool);
    // k=1: row i=4ig+1, prefetch row 4ig+4 -> slot 0
    ldrow(xr, 4, W0[0], W1[0]);
    row_body<1, 2, 3>(W0, W1, dww, pww, pwb, cvw, cvb, pool);
    if (ig == 1) pool_finish<1>(pool, h1a, w1t);   // after row 5
    // k=2: row i=4ig+2, prefetch row 4ig+5 -> slot 1
    ldrow(xr, 5, W0[1], W1[1]);
    row_body<2, 3, 0>(W0, W1, dww, pww, pwb, cvw, cvb, pool);
    if (ig == 0) pool_finish<0>(pool, h1a, w1t);   // after row 2
    // k=3: row i=4ig+3, prefetch row 4ig+6 -> slot 2
    ldrow(xr, 6, W0[2], W1[2]);
    row_body<3, 0, 1>(W0, W1, dww, pww, pwb, cvw, cvb, pool);
  }
  // epilogue: row 8 (slots 0,1,2 hold rows 8,9,10)
  row_body<0, 1, 2>(W0, W1, dww, pww, pwb, cvw, cvb, pool);
  pool_finish<2>(pool, h1a, w1t);

  // combine fc1 partials across the sample's thread pair
#pragma unroll
  for (int o = 0; o < 16; ++o) h1a[o] += __shfl_xor(h1a[o], 1, 64);

  float h1[16];
#pragma unroll
  for (int k = 0; k < 16; ++k) h1[k] = fast_tanh(h1a[k]);

  float h2[16];
#pragma unroll
  for (int o = 0; o < 16; ++o) {
    float acc = b2[o];
#pragma unroll
    for (int k = 0; k < 16; ++k) acc += h1[k] * w2[o * 16 + k];
    h2[o] = fast_tanh(acc);
  }

  // fc3: each thread computes its 7 outputs, stores 28 contiguous bytes
  const int ob = 7 * t;
  float ov[7];
#pragma unroll
  for (int oo = 0; oo < 7; ++oo) {
    float acc = b3[ob + oo];
#pragma unroll
    for (int k = 0; k < 16; ++k) acc += h2[k] * w3[(ob + oo) * 16 + k];
    ov[oo] = acc;
  }
  float* po = out + (long)s * 14 + ob;
  f4v v4; v4[0] = ov[0]; v4[1] = ov[1]; v4[2] = ov[2]; v4[3] = ov[3];
  *reinterpret_cast<f4v*>(po) = v4;
  f2v v2; v2[0] = ov[4]; v2[1] = ov[5];
  *reinterpret_cast<f2v*>(po + 4) = v2;
  po[6] = ov[6];
}

extern "C" void kernel_launch(void* const* d_in, const int* in_sizes, int n_in,
                              void* d_out, int out_size, void* d_ws, size_t ws_size,
                              hipStream_t stream) {
  const float* x      = (const float*)d_in[0];
  const float* dw_w   = (const float*)d_in[1];
  const float* pw_w   = (const float*)d_in[2];
  const float* pw_b   = (const float*)d_in[3];
  const float* conv_w = (const float*)d_in[4];
  const float* conv_b = (const float*)d_in[5];
  const float* w1     = (const float*)d_in[6];
  const float* b1     = (const float*)d_in[7];
  const float* w2     = (const float*)d_in[8];
  const float* b2     = (const float*)d_in[9];
  const float* w3     = (const float*)d_in[10];
  const float* b3     = (const float*)d_in[11];
  float* out = (float*)d_out;

  int nsamp = in_sizes[0] / 546;
  long nthreads = 2L * nsamp;
  int blocks = (int)((nthreads + 255) / 256);
  smartpixel_kernel<<<blocks, 256, 0, stream>>>(
      x, dw_w, pw_w, pw_b, conv_w, conv_b, w1, b1, w2, b2, w3, b3, out, nsamp);
}

// Round 4
// 127.350 us; speedup vs baseline: 2.0097x; 1.9133x over previous
//
#include <hip/hip_runtime.h>

typedef float f4v __attribute__((ext_vector_type(4), aligned(4)));
typedef float f2v __attribute__((ext_vector_type(2), aligned(4)));

__device__ __forceinline__ float fast_tanh(float x) {
  // tanh(x) = 1 - 2/(1 + exp2(x * 2*log2(e)))
  float t = x * 2.8853900817779268f;
  float e = __builtin_amdgcn_exp2f(t);
  float r = __builtin_amdgcn_rcpf(e + 1.0f);
  return 1.0f - 2.0f * r;
}

__global__ __launch_bounds__(256, 3) void smartpixel_kernel(
    const float* __restrict__ x, const float* __restrict__ dww,
    const float* __restrict__ pww, const float* __restrict__ pwb,
    const float* __restrict__ cvw, const float* __restrict__ cvb,
    const float* __restrict__ w1, const float* __restrict__ b1,
    const float* __restrict__ w2, const float* __restrict__ b2,
    const float* __restrict__ w3, const float* __restrict__ b3,
    float* __restrict__ out, int nsamp) {
  const int g = blockIdx.x * 256 + threadIdx.x;
  const int s = g >> 1;          // sample
  const int t = g & 1;           // column-half: t=0 -> out cols 0..8, t=1 -> 9..17
  if (s >= nsamp) return;
  // t=0 reads input cols 0..11; t=1 reads cols 9..20 (needs 11, loads 12)
  const float* xb = x + (long)s * 546 + t * 9;

  // 4-slot rotating row window, two channels, all top-level constant-indexed
  float A0[12], A1[12], A2[12], A3[12];
  float B0[12], B1[12], B2[12], B3[12];

#define LDROW(S, R)                                                        \
  do {                                                                     \
    _Pragma("unroll") for (int kk = 0; kk < 3; ++kk) {                     \
      f4v va = *reinterpret_cast<const f4v*>(xb + (R) * 21 + 4 * kk);      \
      f4v vb = *reinterpret_cast<const f4v*>(xb + 273 + (R) * 21 + 4 * kk);\
      _Pragma("unroll") for (int l = 0; l < 4; ++l) {                      \
        A##S[4 * kk + l] = va[l];                                          \
        B##S[4 * kk + l] = vb[l];                                          \
      }                                                                    \
    }                                                                      \
  } while (0)

  float pool[5][3];
#pragma unroll
  for (int c = 0; c < 5; ++c)
#pragma unroll
    for (int pc = 0; pc < 3; ++pc) pool[c][pc] = 0.0f;

  float h1a[16];
#pragma unroll
  for (int o = 0; o < 16; ++o) h1a[o] = (t == 0) ? b1[o] : 0.0f;

  const float* w1t = w1 + 3 * t;  // this thread's fc1 feature-column base

#define ROWBODY(SA, SB, SC)                                                   \
  do {                                                                        \
    _Pragma("unroll") for (int j = 0; j < 9; ++j) {                           \
      float d0 = A##SA[j] * dww[0] + A##SA[j + 1] * dww[1] + A##SA[j + 2] * dww[2]  \
               + A##SB[j] * dww[3] + A##SB[j + 1] * dww[4] + A##SB[j + 2] * dww[5]  \
               + A##SC[j] * dww[6] + A##SC[j + 1] * dww[7] + A##SC[j + 2] * dww[8]; \
      float d1 = B##SA[j] * dww[9]  + B##SA[j + 1] * dww[10] + B##SA[j + 2] * dww[11] \
               + B##SB[j] * dww[12] + B##SB[j + 1] * dww[13] + B##SB[j + 2] * dww[14] \
               + B##SC[j] * dww[15] + B##SC[j + 1] * dww[16] + B##SC[j + 2] * dww[17];\
      float aa0 = fast_tanh(pwb[0] + pww[0] * d0 + pww[1] * d1);              \
      float aa1 = fast_tanh(pwb[1] + pww[2] * d0 + pww[3] * d1);              \
      float aa2 = fast_tanh(pwb[2] + pww[4] * d0 + pww[5] * d1);              \
      float aa3 = fast_tanh(pwb[3] + pww[6] * d0 + pww[7] * d1);              \
      float aa4 = fast_tanh(pwb[4] + pww[8] * d0 + pww[9] * d1);              \
      _Pragma("unroll") for (int q = 0; q < 5; ++q) {                         \
        float acc = cvb[q] + cvw[5 * q] * aa0 + cvw[5 * q + 1] * aa1          \
                  + cvw[5 * q + 2] * aa2 + cvw[5 * q + 3] * aa3               \
                  + cvw[5 * q + 4] * aa4;                                     \
        pool[q][j / 3] += fast_tanh(acc);                                     \
      }                                                                       \
    }                                                                         \
  } while (0)

#define POOLFIN(RR)                                                           \
  do {                                                                        \
    _Pragma("unroll") for (int c = 0; c < 5; ++c) {                           \
      _Pragma("unroll") for (int pc = 0; pc < 3; ++pc) {                      \
        float pv = fast_tanh(pool[c][pc] * (1.0f / 9.0f));                    \
        pool[c][pc] = 0.0f;                                                   \
        _Pragma("unroll") for (int o = 0; o < 16; ++o) {                      \
          h1a[o] += pv * w1t[o * 90 + c * 18 + (RR) * 6 + pc];                \
        }                                                                     \
      }                                                                       \
    }                                                                         \
  } while (0)

  // static schedule: body i consumes rows i,i+1,i+2; prefetch row i+3 one body ahead
  LDROW(0, 0); LDROW(1, 1); LDROW(2, 2);
  LDROW(3, 3);  ROWBODY(0, 1, 2);               // i=0
  LDROW(0, 4);  ROWBODY(1, 2, 3);               // i=1
  LDROW(1, 5);  ROWBODY(2, 3, 0); POOLFIN(0);   // i=2
  LDROW(2, 6);  ROWBODY(3, 0, 1);               // i=3
  LDROW(3, 7);  ROWBODY(0, 1, 2);               // i=4
  LDROW(0, 8);  ROWBODY(1, 2, 3); POOLFIN(1);   // i=5
  LDROW(1, 9);  ROWBODY(2, 3, 0);               // i=6
  LDROW(2, 10); ROWBODY(3, 0, 1);               // i=7
                ROWBODY(0, 1, 2); POOLFIN(2);   // i=8

  // combine fc1 partials across the sample's thread pair
#pragma unroll
  for (int o = 0; o < 16; ++o) h1a[o] += __shfl_xor(h1a[o], 1, 64);

  float h1[16];
#pragma unroll
  for (int k = 0; k < 16; ++k) h1[k] = fast_tanh(h1a[k]);

  float h2[16];
#pragma unroll
  for (int o = 0; o < 16; ++o) {
    float acc = b2[o];
#pragma unroll
    for (int k = 0; k < 16; ++k) acc += h1[k] * w2[o * 16 + k];
    h2[o] = fast_tanh(acc);
  }

  // fc3: each thread computes its 7 outputs, stores 28 contiguous bytes
  const int ob = 7 * t;
  float ov[7];
#pragma unroll
  for (int oo = 0; oo < 7; ++oo) {
    float acc = b3[ob + oo];
#pragma unroll
    for (int k = 0; k < 16; ++k) acc += h2[k] * w3[(ob + oo) * 16 + k];
    ov[oo] = acc;
  }
  float* po = out + (long)s * 14 + ob;
  f4v v4; v4[0] = ov[0]; v4[1] = ov[1]; v4[2] = ov[2]; v4[3] = ov[3];
  *reinterpret_cast<f4v*>(po) = v4;
  f2v v2; v2[0] = ov[4]; v2[1] = ov[5];
  *reinterpret_cast<f2v*>(po + 4) = v2;
  po[6] = ov[6];
}

extern "C" void kernel_launch(void* const* d_in, const int* in_sizes, int n_in,
                              void* d_out, int out_size, void* d_ws, size_t ws_size,
                              hipStream_t stream) {
  const float* x      = (const float*)d_in[0];
  const float* dw_w   = (const float*)d_in[1];
  const float* pw_w   = (const float*)d_in[2];
  const float* pw_b   = (const float*)d_in[3];
  const float* conv_w = (const float*)d_in[4];
  const float* conv_b = (const float*)d_in[5];
  const float* w1     = (const float*)d_in[6];
  const float* b1     = (const float*)d_in[7];
  const float* w2     = (const float*)d_in[8];
  const float* b2     = (const float*)d_in[9];
  const float* w3     = (const float*)d_in[10];
  const float* b3     = (const float*)d_in[11];
  float* out = (float*)d_out;

  int nsamp = in_sizes[0] / 546;
  long nthreads = 2L * nsamp;
  int blocks = (int)((nthreads + 255) / 256);
  smartpixel_kernel<<<blocks, 256, 0, stream>>>(
      x, dw_w, pw_w, pw_b, conv_w, conv_b, w1, b1, w2, b2, w3, b3, out, nsamp);
}